// Round 8
// baseline (320.361 us; speedup 1.0000x reference)
//
#include <hip/hip_runtime.h>
#include <math.h>

// Problem constants (B=4, T=2048, C=576, H=12, D=48)
#define Bn 4
#define Tn 2048
#define Cn 576
#define Hn 12
#define Dn 48
#define Mn (Bn*Tn)          // 8192 rows

// log2(e) / sqrt(48) — folded into q so attention uses exp2 directly
#define QSCALE (1.4426950408889634f * 0.14433756729740643f)

typedef short  short8  __attribute__((ext_vector_type(8)));   // 8 bf16 (4 VGPRs)
typedef float  floatx4 __attribute__((ext_vector_type(4)));   // MFMA acc
typedef unsigned short ushort_t;

static __device__ __forceinline__ unsigned short f2bf(float f) {
    union { float f; unsigned int u; } v; v.f = f;
    unsigned int r = v.u + 0x7FFFu + ((v.u >> 16) & 1u);   // round-to-nearest-even
    return (unsigned short)(r >> 16);
}

// truncation-pack two fp32 -> packed bf16x2 (P >= 0, rel err <= 2^-8)
static __device__ __forceinline__ unsigned int pack_trunc(float a, float b) {
    union { float f; unsigned int u; } ua, ub; ua.f = a; ub.f = b;
    return (ua.u >> 16) | (ub.u & 0xFFFF0000u);
}

// ---------------------------------------------------------------------------
// fused fp32 -> bf16 cast of all three inputs (one launch)
// ---------------------------------------------------------------------------
__global__ __launch_bounds__(256)
void cast3(const float* __restrict__ a, ushort_t* __restrict__ oa, int na4,
           const float* __restrict__ b, ushort_t* __restrict__ ob, int nb4,
           const float* __restrict__ c, ushort_t* __restrict__ oc, int nc4)
{
    int i = blockIdx.x * 256 + threadIdx.x;
    const float* src; ushort_t* dst; int idx;
    if (i < na4)                  { src = a; dst = oa; idx = i; }
    else if (i < na4 + nb4)       { src = b; dst = ob; idx = i - na4; }
    else if (i < na4 + nb4 + nc4) { src = c; dst = oc; idx = i - na4 - nb4; }
    else return;
    float4 v = ((const float4*)src)[idx];
    ushort4 o;
    o.x = f2bf(v.x); o.y = f2bf(v.y); o.z = f2bf(v.z); o.w = f2bf(v.w);
    ((ushort4*)dst)[idx] = o;
}

// ---------------------------------------------------------------------------
// MFMA bf16 GEMM, REGISTER-STAGED pipeline: out = A[M,576] @ W[N,576]^T.
// Block tile 128(M) x 64(N), BK=32, 4 waves stacked in M. K-steps = 18.
// Pipeline (one barrier per step; NO global_load_lds, so __syncthreads drains
// lgkm only — plain global loads to VGPR stay in flight across barriers):
//   step k: issue global loads (tile k+2 -> VGPR), ds_write tile k+1 -> alt buf
//           (compiler inserts precise vmcnt(N) for those regs, ~1 step slack),
//           ds_read frags of tile k, MFMA, barrier.
// Unrolled x2 so register arrays keep static indices.
// LDS segment-linear frag order (1KB seg = 16 rows x 32 cols; lane l at l*16B).
// MODE 0: scatter q (xQSCALE) / k -> [B,H,T,48]; v -> transposed [B,H,48,T]
// MODE 1: fp32 row-major [M,576]
// ---------------------------------------------------------------------------
template<int MODE>
__global__ __launch_bounds__(256, 4)
void gemm_mfma(const ushort_t* __restrict__ A, const ushort_t* __restrict__ W,
               ushort_t* __restrict__ outb, float* __restrict__ outf)
{
    constexpr int SA = 8, NSEG = 12, NC = 3;   // A segs, total segs, chunks/thread
    constexpr int NB = (MODE == 0) ? 27 : 9;
    constexpr int NSTEP = Cn / 32;             // 18
    __shared__ __align__(16) ushort_t Ls[2][NSEG][512];

    const int tid  = threadIdx.x;
    const int wave = tid >> 6;
    const int lane = tid & 63;
    const int m    = lane & 15;
    const int g    = lane >> 4;
    const int bid  = blockIdx.x;
    const int n0   = (bid % NB) * 64;
    const int m0   = (bid / NB) * 128;

    floatx4 acc[2][4];
    #pragma unroll
    for (int i = 0; i < 2; ++i)
        #pragma unroll
        for (int j = 0; j < 4; ++j)
            acc[i][j] = (floatx4){0.f, 0.f, 0.f, 0.f};

    // chunk descriptors: sigma = i*256+tid; seg = sigma>>6 (one seg per wave+i)
    const char* gp[NC];
    int segi[NC], loff[NC];
    #pragma unroll
    for (int i = 0; i < NC; ++i) {
        int s = i * 4 + wave;        // seg index
        segi[i] = s;
        loff[i] = lane * 8;          // ushort offset of this lane's 16B slot
        gp[i] = (s < SA)
            ? (const char*)(A + (size_t)(m0 + s * 16 + m) * Cn + g * 8)
            : (const char*)(W + (size_t)(n0 + (s - SA) * 16 + m) * Cn + g * 8);
    }

    float4 vga[NC], vgb[NC];
    #pragma unroll
    for (int i = 0; i < NC; ++i) { vga[i] = *(const float4*)gp[i]; gp[i] += 64; }
    #pragma unroll
    for (int i = 0; i < NC; ++i) { vgb[i] = *(const float4*)gp[i]; gp[i] += 64; }
    #pragma unroll
    for (int i = 0; i < NC; ++i) *(float4*)&Ls[0][segi[i]][loff[i]] = vga[i];
    __syncthreads();

    #pragma unroll 1
    for (int k2 = 0; k2 < NSTEP; k2 += 2) {
        // ---- step A: compute tile k2 (buf0); stage k2+1 -> buf1; load k2+2 ----
        if (k2 + 2 < NSTEP) {
            #pragma unroll
            for (int i = 0; i < NC; ++i) { vga[i] = *(const float4*)gp[i]; gp[i] += 64; }
        }
        #pragma unroll
        for (int i = 0; i < NC; ++i) *(float4*)&Ls[1][segi[i]][loff[i]] = vgb[i];
        {
            short8 bf4[4];
            #pragma unroll
            for (int j = 0; j < 4; ++j) bf4[j] = *(const short8*)&Ls[0][SA + j][lane * 8];
            #pragma unroll
            for (int i = 0; i < 2; ++i) {
                short8 af = *(const short8*)&Ls[0][wave * 2 + i][lane * 8];
                #pragma unroll
                for (int j = 0; j < 4; ++j)
                    acc[i][j] = __builtin_amdgcn_mfma_f32_16x16x32_bf16(af, bf4[j], acc[i][j], 0, 0, 0);
            }
        }
        __syncthreads();
        // ---- step B: compute tile k2+1 (buf1); stage k2+2 -> buf0; load k2+3 ----
        if (k2 + 3 < NSTEP) {
            #pragma unroll
            for (int i = 0; i < NC; ++i) { vgb[i] = *(const float4*)gp[i]; gp[i] += 64; }
        }
        if (k2 + 2 < NSTEP) {
            #pragma unroll
            for (int i = 0; i < NC; ++i) *(float4*)&Ls[0][segi[i]][loff[i]] = vga[i];
        }
        {
            short8 bf4[4];
            #pragma unroll
            for (int j = 0; j < 4; ++j) bf4[j] = *(const short8*)&Ls[1][SA + j][lane * 8];
            #pragma unroll
            for (int i = 0; i < 2; ++i) {
                short8 af = *(const short8*)&Ls[1][wave * 2 + i][lane * 8];
                #pragma unroll
                for (int j = 0; j < 4; ++j)
                    acc[i][j] = __builtin_amdgcn_mfma_f32_16x16x32_bf16(af, bf4[j], acc[i][j], 0, 0, 0);
            }
        }
        __syncthreads();
    }

    // epilogue: C/D layout col = lane&15 (n), row = (lane>>4)*4 + reg (m)
    const size_t per = (size_t)Bn * Hn * Tn * Dn;
    if (MODE == 0) {
        const int which = n0 / Cn;                 // 64-col block fits in one of q/k/v
        const int nb    = n0 - which * Cn;
        #pragma unroll
        for (int i = 0; i < 2; ++i) {
            int mrow0 = m0 + wave * 32 + i * 16 + g * 4;
            int b  = mrow0 >> 11;
            int t0 = mrow0 & 2047;
            #pragma unroll
            for (int j = 0; j < 4; ++j) {
                int n = nb + j * 16 + m;
                int h = n / 48;
                int d = n - h * 48;
                if (which == 2) {
                    ushort4 pk;
                    pk.x = f2bf(acc[i][j][0]); pk.y = f2bf(acc[i][j][1]);
                    pk.z = f2bf(acc[i][j][2]); pk.w = f2bf(acc[i][j][3]);
                    *(ushort4*)&outb[2 * per + (((size_t)(b * Hn + h) * Dn + d) * Tn) + t0] = pk;
                } else {
                    float sc = (which == 0) ? QSCALE : 1.0f;
                    size_t base = (size_t)which * per + (((size_t)(b * Hn + h) * Tn + t0) * Dn) + d;
                    #pragma unroll
                    for (int r = 0; r < 4; ++r)
                        outb[base + (size_t)r * Dn] = f2bf(acc[i][j][r] * sc);
                }
            }
        }
    } else {
        #pragma unroll
        for (int i = 0; i < 2; ++i) {
            #pragma unroll
            for (int r = 0; r < 4; ++r) {
                int mrow = m0 + wave * 32 + i * 16 + g * 4 + r;
                #pragma unroll
                for (int j = 0; j < 4; ++j)
                    outf[(size_t)mrow * Cn + n0 + j * 16 + m] = acc[i][j][r];
            }
        }
    }
}

// ---------------------------------------------------------------------------
// Flash attention via S^T, no-max softmax, bf16 MFMA.
// Q-tile 64, 256 threads (4 waves x 16 queries). 1D grid of 1536 blocks,
// largest-qt-first -> real queue (1024 slots) -> LPT load balance (fixes the
// round-7 CU-correlation imbalance: 3 same-QT blocks per CU).
// K/V staging: REGISTER prefetch (global_load -> VGPR at iter start, ds_write
// at iter end) — no global_load_lds, so per-iter __syncthreads drains lgkm
// only; the loads keep ~1 full iteration of slack. Pads are zero registers.
// LDS 36KB -> 4 blocks/CU (16 waves).
// ---------------------------------------------------------------------------
__global__ __launch_bounds__(256, 4)
void attn_mfma(const ushort_t* __restrict__ Q, const ushort_t* __restrict__ K,
               const ushort_t* __restrict__ V, ushort_t* __restrict__ Y)
{
    __shared__ __align__(16) ushort_t QPs[8][512];     // Q tile, then reused as P^T
    __shared__ __align__(16) ushort_t Ks[2][8][512];   // [buf][(ktile t, kc)]
    __shared__ __align__(16) ushort_t Vs[2][6][512];   // [buf][(dtile t, kc)]

    const int id   = blockIdx.x;       // 0..1535
    const int qt   = 31 - (id / 48);   // largest first
    const int bh   = id % 48;
    const int tid  = threadIdx.x;
    const int wave = tid >> 6;         // 0..3
    const int lane = tid & 63;
    const int m    = lane & 15;
    const int g    = lane >> 4;
    const int q0   = qt * 64;
    const int nkt  = qt + 1;           // 64-row K tiles

    const ushort_t* Qp = Q + (size_t)bh * Tn * Dn;
    const ushort_t* Kp = K + (size_t)bh * Tn * Dn;
    const ushort_t* Vp = V + (size_t)bh * Dn * Tn;     // [48][T]

    const float4 z4 = {0.f, 0.f, 0.f, 0.f};
    const bool   gv = (g < 2);         // kc=1 columns 32..47 real, 48..63 pad

    // per-lane staging pointers (advance per tile)
    const ushort_t* kp = Kp + (size_t)(wave * 16 + m) * Dn + g * 8;     // kc=0
    const ushort_t* vp = Vp + (size_t)(wave * 16 + m) * Tn + g * 8;     // kc=0 (w<3)

    // ---- prologue: Q + K/V tile 0 via registers ----
    {
        const ushort_t* qp = Qp + (size_t)(q0 + wave * 16 + m) * Dn + g * 8;
        float4 q0v = *(const float4*)qp;
        float4 q1v = gv ? *(const float4*)(qp + 32) : z4;
        float4 k0v = *(const float4*)kp;
        float4 k1v = gv ? *(const float4*)(kp + 32) : z4;
        *(float4*)&QPs[wave * 2 + 0][lane * 8] = q0v;
        *(float4*)&QPs[wave * 2 + 1][lane * 8] = q1v;
        *(float4*)&Ks[0][wave * 2 + 0][lane * 8] = k0v;
        *(float4*)&Ks[0][wave * 2 + 1][lane * 8] = k1v;
        if (wave < 3) {
            float4 v0v = *(const float4*)vp;
            float4 v1v = *(const float4*)(vp + 32);
            *(float4*)&Vs[0][wave * 2 + 0][lane * 8] = v0v;
            *(float4*)&Vs[0][wave * 2 + 1][lane * 8] = v1v;
        }
        kp += 64 * Dn;   // tile 1
        vp += 64;
    }
    __syncthreads();

    // loop-invariant B-fragments (Q); QPs strip then dead -> reused for P^T
    short8 bq[2];
    bq[0] = *(const short8*)&QPs[wave * 2 + 0][lane * 8];
    bq[1] = *(const short8*)&QPs[wave * 2 + 1][lane * 8];

    floatx4 acc[3];
    #pragma unroll
    for (int t = 0; t < 3; ++t) acc[t] = (floatx4){0.f, 0.f, 0.f, 0.f};
    float l_tot = 0.f;
    const int qrow = q0 + wave * 16 + m;    // this lane's global query row

    for (int jt = 0; jt < nkt; ++jt) {
        const int cur = jt & 1;
        // ---- issue register prefetch of tile jt+1 (no LDS writes yet) ----
        float4 k0v, k1v, v0v, v1v;
        const bool more = (jt + 1 < nkt);
        if (more) {
            k0v = *(const float4*)kp;
            k1v = gv ? *(const float4*)(kp + 32) : z4;
            if (wave < 3) {
                v0v = *(const float4*)vp;
                v1v = *(const float4*)(vp + 32);
            }
            kp += 64 * Dn;
            vp += 64;
        }

        // ---- S^T = K Q^T : D[m=j (4 tiles)][n=q] ----
        floatx4 s[4];
        #pragma unroll
        for (int t = 0; t < 4; ++t) {
            s[t] = (floatx4){0.f, 0.f, 0.f, 0.f};
            #pragma unroll
            for (int kc = 0; kc < 2; ++kc) {
                short8 ak = *(const short8*)&Ks[cur][t * 2 + kc][lane * 8];
                s[t] = __builtin_amdgcn_mfma_f32_16x16x32_bf16(ak, bq[kc], s[t], 0, 0, 0);
            }
        }

        // ---- mask (diagonal tile = last) + exp2 + in-lane partial row-sum ----
        float p[4][4];
        float lsum = 0.f;
        if (jt == qt) {
            const int j0 = jt * 64;
            #pragma unroll
            for (int t = 0; t < 4; ++t)
                #pragma unroll
                for (int r = 0; r < 4; ++r) {
                    int j = j0 + t * 16 + g * 4 + r;
                    float v = (j <= qrow) ? s[t][r] : -1e30f;
                    float e = __builtin_amdgcn_exp2f(v);
                    p[t][r] = e; lsum += e;
                }
        } else {
            #pragma unroll
            for (int t = 0; t < 4; ++t)
                #pragma unroll
                for (int r = 0; r < 4; ++r) {
                    float e = __builtin_amdgcn_exp2f(s[t][r]);
                    p[t][r] = e; lsum += e;
                }
        }
        lsum += __shfl_xor(lsum, 16);
        lsum += __shfl_xor(lsum, 32);
        l_tot += lsum;

        // ---- store P^T in B-frag order into the (dead) Q strip ----
        #pragma unroll
        for (int t = 0; t < 4; ++t) {
            uint2 w2;
            w2.x = pack_trunc(p[t][0], p[t][1]);
            w2.y = pack_trunc(p[t][2], p[t][3]);
            *(uint2*)&QPs[wave * 2 + (t >> 1)]
                         [(2 * (t & 1) + (g >> 1)) * 128 + m * 8 + (g & 1) * 4] = w2;
        }
        // wave-private strip: drain this wave's LDS writes, no barrier needed
        asm volatile("s_waitcnt lgkmcnt(0)" ::: "memory");

        // ---- O^T += V^T P^T : D[m=d (3 tiles)][n=q] ----
        #pragma unroll
        for (int kc = 0; kc < 2; ++kc) {
            short8 bp = *(const short8*)&QPs[wave * 2 + kc][lane * 8];
            #pragma unroll
            for (int t = 0; t < 3; ++t) {
                short8 av = *(const short8*)&Vs[cur][t * 2 + kc][lane * 8];
                acc[t] = __builtin_amdgcn_mfma_f32_16x16x32_bf16(av, bp, acc[t], 0, 0, 0);
            }
        }

        // ---- stage tile jt+1 into the other buffer (vmcnt waits land here) ----
        if (more) {
            const int nxt = cur ^ 1;
            *(float4*)&Ks[nxt][wave * 2 + 0][lane * 8] = k0v;
            *(float4*)&Ks[nxt][wave * 2 + 1][lane * 8] = k1v;
            if (wave < 3) {
                *(float4*)&Vs[nxt][wave * 2 + 0][lane * 8] = v0v;
                *(float4*)&Vs[nxt][wave * 2 + 1][lane * 8] = v1v;
            }
        }
        __syncthreads();   // lgkm drain only — no global_load_lds outstanding
    }

    // ---- epilogue: lane holds O^T[d = t*16+g*4+r][qrow]; normalize, store ----
    const float inv = 1.0f / l_tot;
    const int b = bh / Hn;
    const int h = bh - b * Hn;
    ushort_t* yp = Y + ((size_t)(b * Tn + qrow)) * Cn + h * Dn;
    #pragma unroll
    for (int t = 0; t < 3; ++t) {
        ushort4 o;
        o.x = f2bf(acc[t][0] * inv);
        o.y = f2bf(acc[t][1] * inv);
        o.z = f2bf(acc[t][2] * inv);
        o.w = f2bf(acc[t][3] * inv);
        *(ushort4*)&yp[t * 16 + g * 4] = o;
    }
}

// ---------------------------------------------------------------------------
extern "C" void kernel_launch(void* const* d_in, const int* in_sizes, int n_in,
                              void* d_out, int out_size, void* d_ws, size_t ws_size,
                              hipStream_t stream)
{
    const float* x      = (const float*)d_in[0];   // [B,T,C]
    const float* w_qkv  = (const float*)d_in[1];   // [3C,C]
    const float* w_proj = (const float*)d_in[2];   // [C,C]
    float* out = (float*)d_out;                    // [B,T,C] fp32

    const size_t per = (size_t)Bn * Hn * Tn * Dn;  // 4,718,592

    ushort_t* xb  = (ushort_t*)d_ws;               // 8192*576
    ushort_t* wqb = xb  + (size_t)Mn * Cn;         // 1728*576
    ushort_t* wpb = wqb + (size_t)3 * Cn * Cn;     // 576*576
    ushort_t* qkv = wpb + (size_t)Cn * Cn;         // 3*per (q | k | v^T)
    ushort_t* yb  = qkv + 3 * per;                 // 8192*576

    // fused casts (fp32 -> bf16)
    const int na4 = Mn * Cn / 4, nb4 = 3 * Cn * Cn / 4, nc4 = Cn * Cn / 4;
    cast3<<<dim3((na4 + nb4 + nc4 + 255) / 256), dim3(256), 0, stream>>>(
        x, xb, na4, w_qkv, wqb, nb4, w_proj, wpb, nc4);

    // QKV GEMM (M=8192, N=1728): q scaled, k natural, v transposed; 1728 blocks
    gemm_mfma<0><<<dim3((Mn / 128) * 27), dim3(256), 0, stream>>>(xb, wqb, qkv, nullptr);

    // causal attention (ALiBi bias is exactly zero on the unmasked region)
    attn_mfma<<<dim3((Tn / 64) * Bn * Hn), dim3(256), 0, stream>>>(qkv, qkv + per, qkv + 2 * per, yb);

    // output projection (M=8192, N=576) -> fp32; 576 blocks
    gemm_mfma<1><<<dim3((Mn / 128) * 9), dim3(256), 0, stream>>>(yb, wpb, nullptr, out);
}

// Round 9
// 300.075 us; speedup vs baseline: 1.0676x; 1.0676x over previous
//
#include <hip/hip_runtime.h>
#include <math.h>

// Problem constants (B=4, T=2048, C=576, H=12, D=48)
#define Bn 4
#define Tn 2048
#define Cn 576
#define Hn 12
#define Dn 48
#define Mn (Bn*Tn)          // 8192 rows

// log2(e) / sqrt(48) — folded into q so attention uses exp2 directly
#define QSCALE (1.4426950408889634f * 0.14433756729740643f)

typedef short  short8  __attribute__((ext_vector_type(8)));   // 8 bf16 (4 VGPRs)
typedef float  floatx4 __attribute__((ext_vector_type(4)));   // MFMA acc
typedef unsigned short ushort_t;
typedef unsigned short ushort8_t __attribute__((ext_vector_type(8))); // 16B

static __device__ __forceinline__ unsigned short f2bf(float f) {
    union { float f; unsigned int u; } v; v.f = f;
    unsigned int r = v.u + 0x7FFFu + ((v.u >> 16) & 1u);   // round-to-nearest-even
    return (unsigned short)(r >> 16);
}

// truncation-pack two fp32 -> packed bf16x2 (P >= 0, rel err <= 2^-8)
static __device__ __forceinline__ unsigned int pack_trunc(float a, float b) {
    union { float f; unsigned int u; } ua, ub; ua.f = a; ub.f = b;
    return (ua.u >> 16) | (ub.u & 0xFFFF0000u);
}

// async global->LDS, 16B per lane; lane l's data lands at lds + l*16 (lane-linear)
static __device__ __forceinline__ void gload16(void* lds, const void* g) {
    __builtin_amdgcn_global_load_lds(
        (const __attribute__((address_space(1))) void*)g,
        (__attribute__((address_space(3))) void*)lds, 16, 0, 0);
}

// ---------------------------------------------------------------------------
// fused fp32 -> bf16 cast of all three inputs (one launch)
// ---------------------------------------------------------------------------
__global__ __launch_bounds__(256)
void cast3(const float* __restrict__ a, ushort_t* __restrict__ oa, int na4,
           const float* __restrict__ b, ushort_t* __restrict__ ob, int nb4,
           const float* __restrict__ c, ushort_t* __restrict__ oc, int nc4)
{
    int i = blockIdx.x * 256 + threadIdx.x;
    const float* src; ushort_t* dst; int idx;
    if (i < na4)                  { src = a; dst = oa; idx = i; }
    else if (i < na4 + nb4)       { src = b; dst = ob; idx = i - na4; }
    else if (i < na4 + nb4 + nc4) { src = c; dst = oc; idx = i - na4 - nb4; }
    else return;
    float4 v = ((const float4*)src)[idx];
    ushort4 o;
    o.x = f2bf(v.x); o.y = f2bf(v.y); o.z = f2bf(v.z); o.w = f2bf(v.w);
    ((ushort4*)dst)[idx] = o;
}

// ---------------------------------------------------------------------------
// MFMA bf16 GEMM, register-staged pipeline: out = A[M,576] @ W[N,576]^T.
// Block tile 128(M) x 64(N), BK=32, 4 waves stacked in M. 18 K-steps, x2 unroll.
// XCD SWIZZLE: bid = xcd + 8*slot; m-group = xcd + 8*(slot/NB); n = slot%NB.
// All NB blocks sharing one A-tile land on ONE XCD -> A fetched ~once from HBM,
// W stays resident in that XCD's 4MB L2 (W_qkv = 2MB).
// COALESCED EPILOGUE (MODE 0): C-tile staged to LDS (reusing staging buffers),
// then cooperative 16B-chunk writes: q/k row-major (96B head-runs), v via LDS
// transpose -> 256B contiguous runs in [B,H,48,T]. Kills the 13.7x write
// amplification of the old per-lane scatter.
// MODE 1: fp32 row-major [M,576] direct (already coalesced: 64B runs).
// ---------------------------------------------------------------------------
template<int MODE>
__global__ __launch_bounds__(256, 4)
void gemm_mfma(const ushort_t* __restrict__ A, const ushort_t* __restrict__ W,
               ushort_t* __restrict__ outb, float* __restrict__ outf)
{
    constexpr int SA = 8, NSEG = 12, NC = 3;   // A segs, total segs, chunks/thread
    constexpr int NB = (MODE == 0) ? 27 : 9;
    constexpr int NSTEP = Cn / 32;             // 18
    __shared__ __align__(16) ushort_t Ls[2][NSEG][512];   // 24 KB

    const int tid  = threadIdx.x;
    const int wave = tid >> 6;
    const int lane = tid & 63;
    const int m    = lane & 15;
    const int g    = lane >> 4;
    const int bid  = blockIdx.x;
    const int xcd  = bid & 7;
    const int slot = bid >> 3;
    const int n0   = (slot % NB) * 64;
    const int m0   = (xcd + 8 * (slot / NB)) * 128;

    floatx4 acc[2][4];
    #pragma unroll
    for (int i = 0; i < 2; ++i)
        #pragma unroll
        for (int j = 0; j < 4; ++j)
            acc[i][j] = (floatx4){0.f, 0.f, 0.f, 0.f};

    const char* gp[NC];
    int segi[NC];
    #pragma unroll
    for (int i = 0; i < NC; ++i) {
        int s = i * 4 + wave;        // segs {wave, wave+4, wave+8}
        segi[i] = s;
        gp[i] = (s < SA)
            ? (const char*)(A + (size_t)(m0 + s * 16 + m) * Cn + g * 8)
            : (const char*)(W + (size_t)(n0 + (s - SA) * 16 + m) * Cn + g * 8);
    }

    float4 vga[NC], vgb[NC];
    #pragma unroll
    for (int i = 0; i < NC; ++i) { vga[i] = *(const float4*)gp[i]; gp[i] += 64; }
    #pragma unroll
    for (int i = 0; i < NC; ++i) { vgb[i] = *(const float4*)gp[i]; gp[i] += 64; }
    #pragma unroll
    for (int i = 0; i < NC; ++i) *(float4*)&Ls[0][segi[i]][lane * 8] = vga[i];
    __syncthreads();

    #pragma unroll 1
    for (int k2 = 0; k2 < NSTEP; k2 += 2) {
        // ---- step A: compute tile k2 (buf0); stage k2+1 -> buf1; load k2+2 ----
        if (k2 + 2 < NSTEP) {
            #pragma unroll
            for (int i = 0; i < NC; ++i) { vga[i] = *(const float4*)gp[i]; gp[i] += 64; }
        }
        #pragma unroll
        for (int i = 0; i < NC; ++i) *(float4*)&Ls[1][segi[i]][lane * 8] = vgb[i];
        {
            short8 bf4[4];
            #pragma unroll
            for (int j = 0; j < 4; ++j) bf4[j] = *(const short8*)&Ls[0][SA + j][lane * 8];
            #pragma unroll
            for (int i = 0; i < 2; ++i) {
                short8 af = *(const short8*)&Ls[0][wave * 2 + i][lane * 8];
                #pragma unroll
                for (int j = 0; j < 4; ++j)
                    acc[i][j] = __builtin_amdgcn_mfma_f32_16x16x32_bf16(af, bf4[j], acc[i][j], 0, 0, 0);
            }
        }
        __syncthreads();
        // ---- step B: compute tile k2+1 (buf1); stage k2+2 -> buf0; load k2+3 ----
        if (k2 + 3 < NSTEP) {
            #pragma unroll
            for (int i = 0; i < NC; ++i) { vgb[i] = *(const float4*)gp[i]; gp[i] += 64; }
        }
        if (k2 + 2 < NSTEP) {
            #pragma unroll
            for (int i = 0; i < NC; ++i) *(float4*)&Ls[0][segi[i]][lane * 8] = vga[i];
        }
        {
            short8 bf4[4];
            #pragma unroll
            for (int j = 0; j < 4; ++j) bf4[j] = *(const short8*)&Ls[1][SA + j][lane * 8];
            #pragma unroll
            for (int i = 0; i < 2; ++i) {
                short8 af = *(const short8*)&Ls[1][wave * 2 + i][lane * 8];
                #pragma unroll
                for (int j = 0; j < 4; ++j)
                    acc[i][j] = __builtin_amdgcn_mfma_f32_16x16x32_bf16(af, bf4[j], acc[i][j], 0, 0, 0);
            }
        }
        __syncthreads();
    }

    // ---- epilogue: C/D layout col = lane&15 (n), row = (lane>>4)*4 + reg ----
    const size_t per = (size_t)Bn * Hn * Tn * Dn;
    const int b   = m0 >> 11;       // tile never straddles batch (128 | 2048)
    const int t0g = m0 & 2047;
    if (MODE == 0) {
        const int which = n0 / Cn;
        const int nb    = n0 - which * Cn;
        ushort_t* Lc = (ushort_t*)&Ls[0][0][0];
        if (which == 2) {
            // stage transposed: Lv[col(64)][row(128)+8 pad] — ushort4 per 4 rows
            #pragma unroll
            for (int i = 0; i < 2; ++i)
                #pragma unroll
                for (int j = 0; j < 4; ++j) {
                    ushort4 pk;
                    pk.x = f2bf(acc[i][j][0]); pk.y = f2bf(acc[i][j][1]);
                    pk.z = f2bf(acc[i][j][2]); pk.w = f2bf(acc[i][j][3]);
                    *(ushort4*)&Lc[(j * 16 + m) * 136 + wave * 32 + i * 16 + g * 4] = pk;
                }
            __syncthreads();
            // write [B,H,48,T]: 16B = 8 consecutive t (256B runs per (h,d))
            #pragma unroll
            for (int it = 0; it < 4; ++it) {
                int c    = tid + it * 256;          // 0..1023
                int col  = c >> 4;
                int rowc = (c & 15) * 8;
                int n    = nb + col;
                int h    = n / 48;
                int d    = n - h * 48;
                ushort_t* dst = outb + 2 * per
                    + (((size_t)(b * Hn + h) * Dn + d) * Tn) + t0g + rowc;
                *(ushort8_t*)dst = *(const ushort8_t*)&Lc[col * 136 + rowc];
            }
        } else {
            const float sc = (which == 0) ? QSCALE : 1.0f;
            // stage row-major: Lr[row(128)][col(64)+16 pad] (160B stride, 16B-aligned)
            #pragma unroll
            for (int i = 0; i < 2; ++i)
                #pragma unroll
                for (int j = 0; j < 4; ++j)
                    #pragma unroll
                    for (int r = 0; r < 4; ++r)
                        Lc[(wave * 32 + i * 16 + g * 4 + r) * 80 + j * 16 + m] =
                            f2bf(acc[i][j][r] * sc);
            __syncthreads();
            // write [B,H,T,48]: 16B chunks never straddle a head (8 | 48)
            #pragma unroll
            for (int it = 0; it < 4; ++it) {
                int c   = tid + it * 256;           // 0..1023
                int row = c >> 3;
                int c8  = (c & 7) * 8;
                int n   = nb + c8;
                int h   = n / 48;
                int d   = n - h * 48;
                ushort_t* dst = outb + (size_t)which * per
                    + (((size_t)(b * Hn + h) * Tn + t0g + row) * Dn) + d;
                *(ushort8_t*)dst = *(const ushort8_t*)&Lc[row * 80 + c8];
            }
        }
    } else {
        #pragma unroll
        for (int i = 0; i < 2; ++i) {
            #pragma unroll
            for (int r = 0; r < 4; ++r) {
                int mrow = m0 + wave * 32 + i * 16 + g * 4 + r;
                #pragma unroll
                for (int j = 0; j < 4; ++j)
                    outf[(size_t)mrow * Cn + n0 + j * 16 + m] = acc[i][j][r];
            }
        }
    }
}

// ---------------------------------------------------------------------------
// Flash attention via S^T, no-max softmax, bf16 MFMA (round-7 kernel, measured
// 64.3us). CHANGE: 1D interleaved-qt grid. Co-resident blocks on a CU are ids
// {c, c+256, c+512}; with qt = k&1 ? k>>1 : 15-k>>1 (k=id/48) each CU's three
// blocks sum to ~25+-2 tile-iters (was 18..33 -> 1.8x makespan skew).
// Q-tile 128, 512 threads (8 waves x 16 q). K-tile 64, double-buffered
// global_load_lds staging, lane-linear segments. Ps aliases dead Q strip.
// ---------------------------------------------------------------------------
__global__ __launch_bounds__(512, 6)
void attn_mfma(const ushort_t* __restrict__ Q, const ushort_t* __restrict__ K,
               const ushort_t* __restrict__ V, ushort_t* __restrict__ Y,
               const ushort_t* __restrict__ zb)
{
    __shared__ __align__(16) ushort_t QPs[16][512];    // Q tile, then reused as P^T
    __shared__ __align__(16) ushort_t Ks[2][8][512];   // [buf][(ktile t, kc)]
    __shared__ __align__(16) ushort_t Vs[2][6][512];   // [buf][(dtile t, kc)]

    const int id   = blockIdx.x;
    const int kk   = id / 48;
    const int bh   = id - kk * 48;
    const int QT   = (kk & 1) ? (kk >> 1) : (15 - (kk >> 1));   // interleave big/small
    const int tid  = threadIdx.x;
    const int wave = tid >> 6;       // 0..7
    const int lane = tid & 63;
    const int m    = lane & 15;
    const int g    = lane >> 4;
    const int q0   = QT * 128;
    const int nkt  = 2 * QT + 2;     // 64-row K tiles to process

    const ushort_t* Qp = Q + (size_t)bh * Tn * Dn;
    const ushort_t* Kp = K + (size_t)bh * Tn * Dn;
    const ushort_t* Vp = V + (size_t)bh * Dn * Tn;     // [48][T]

    // ---- Q staging: wave w stages segs 2w,2w+1 (rows q0+w*16+m); pad -> zeros ----
    {
        const char* qrp = (const char*)(Qp + (size_t)(q0 + wave * 16 + m) * Dn);
        gload16(&QPs[wave * 2 + 0][0], qrp + g * 16);
        gload16(&QPs[wave * 2 + 1][0], (g < 2) ? (qrp + 64 + g * 16) : (const char*)zb);
    }

    // ---- per-lane K/V staging pointers (wave w owns K seg w; V seg w for w<6) ----
    const bool  kpad = ((wave & 1) == 1) && (g >= 2);
    const char* kptr = kpad ? (const char*)zb
        : (const char*)(Kp + (size_t)((wave >> 1) * 16 + m) * Dn) + (wave & 1) * 64 + g * 16;
    const int   kadv = kpad ? 0 : 64 * Dn * 2;         // 64 K-rows per tile
    const char* vptr = (const char*)(Vp + (size_t)((wave >> 1) * 16 + m) * Tn)
                       + (wave & 1) * 64 + g * 16;     // valid only for wave<6
    const int   vadv = 64 * 2;                         // 64 V^T-cols per tile

    // prologue: stage K/V tile 0 into buf 0
    gload16(&Ks[0][wave][0], kptr); kptr += kadv;
    if (wave < 6) { gload16(&Vs[0][wave][0], vptr); vptr += vadv; }
    __syncthreads();   // drains vmcnt -> Q + tile0 ready

    // loop-invariant B-fragments (Q); QPs strip (wave-private) then dead -> P^T
    short8 bq[2];
    bq[0] = *(const short8*)&QPs[wave * 2 + 0][lane * 8];
    bq[1] = *(const short8*)&QPs[wave * 2 + 1][lane * 8];

    floatx4 acc[3];
    #pragma unroll
    for (int t = 0; t < 3; ++t) acc[t] = (floatx4){0.f, 0.f, 0.f, 0.f};
    float l_tot = 0.f;
    const int qrow  = q0 + wave * 16 + m;    // this lane's global query row
    const int qwmin = q0 + wave * 16;        // wave's min query row
    const int qwmax = qwmin + 15;            // wave's max query row

    for (int jt = 0; jt < nkt; ++jt) {
        const int cur = jt & 1;
        const int j0  = jt * 64;
        // issue async staging for tile jt+1 (overlaps this tile's compute)
        if (jt + 1 < nkt) {
            gload16(&Ks[cur ^ 1][wave][0], kptr); kptr += kadv;
            if (wave < 6) { gload16(&Vs[cur ^ 1][wave][0], vptr); vptr += vadv; }
        }

        if (j0 <= qwmax) {   // wave-uniform: at least one unmasked element
            // ---- S^T = K Q^T : D[m=j (4 tiles)][n=q] ----
            floatx4 s[4];
            #pragma unroll
            for (int t = 0; t < 4; ++t) {
                s[t] = (floatx4){0.f, 0.f, 0.f, 0.f};
                #pragma unroll
                for (int kc = 0; kc < 2; ++kc) {
                    short8 ak = *(const short8*)&Ks[cur][t * 2 + kc][lane * 8];
                    s[t] = __builtin_amdgcn_mfma_f32_16x16x32_bf16(ak, bq[kc], s[t], 0, 0, 0);
                }
            }

            // ---- mask (only if tile straddles diagonal) + exp2 + partial sum ----
            float p[4][4];
            float lsum = 0.f;
            if (j0 + 63 > qwmin) {
                #pragma unroll
                for (int t = 0; t < 4; ++t)
                    #pragma unroll
                    for (int r = 0; r < 4; ++r) {
                        int j = j0 + t * 16 + g * 4 + r;
                        float v = (j <= qrow) ? s[t][r] : -1e30f;
                        float e = __builtin_amdgcn_exp2f(v);
                        p[t][r] = e; lsum += e;
                    }
            } else {
                #pragma unroll
                for (int t = 0; t < 4; ++t)
                    #pragma unroll
                    for (int r = 0; r < 4; ++r) {
                        float e = __builtin_amdgcn_exp2f(s[t][r]);
                        p[t][r] = e; lsum += e;
                    }
            }
            lsum += __shfl_xor(lsum, 16);
            lsum += __shfl_xor(lsum, 32);
            l_tot += lsum;

            // ---- store P^T in B-frag order into the (dead) Q strip ----
            #pragma unroll
            for (int t = 0; t < 4; ++t) {
                uint2 w2;
                w2.x = pack_trunc(p[t][0], p[t][1]);
                w2.y = pack_trunc(p[t][2], p[t][3]);
                *(uint2*)&QPs[wave * 2 + (t >> 1)]
                             [(2 * (t & 1) + (g >> 1)) * 128 + m * 8 + (g & 1) * 4] = w2;
            }
            // wave-private strip: drain this wave's LDS writes, no barrier needed
            asm volatile("s_waitcnt lgkmcnt(0)" ::: "memory");

            // ---- O^T += V^T P^T : D[m=d (3 tiles)][n=q] ----
            #pragma unroll
            for (int kc = 0; kc < 2; ++kc) {
                short8 bp = *(const short8*)&QPs[wave * 2 + kc][lane * 8];
                #pragma unroll
                for (int t = 0; t < 3; ++t) {
                    short8 av = *(const short8*)&Vs[cur][t * 2 + kc][lane * 8];
                    acc[t] = __builtin_amdgcn_mfma_f32_16x16x32_bf16(av, bp, acc[t], 0, 0, 0);
                }
            }
        }

        __syncthreads();   // next tile staged (vmcnt drain) + cur-buf reads done
    }

    // ---- epilogue: lane holds O^T[d = t*16+g*4+r][qrow]; normalize, store ----
    const float inv = 1.0f / l_tot;
    const int b = bh / Hn;
    const int h = bh - b * Hn;
    ushort_t* yp = Y + ((size_t)(b * Tn + qrow)) * Cn + h * Dn;
    #pragma unroll
    for (int t = 0; t < 3; ++t) {
        ushort4 o;
        o.x = f2bf(acc[t][0] * inv);
        o.y = f2bf(acc[t][1] * inv);
        o.z = f2bf(acc[t][2] * inv);
        o.w = f2bf(acc[t][3] * inv);
        *(ushort4*)&yp[t * 16 + g * 4] = o;
    }
}

// ---------------------------------------------------------------------------
extern "C" void kernel_launch(void* const* d_in, const int* in_sizes, int n_in,
                              void* d_out, int out_size, void* d_ws, size_t ws_size,
                              hipStream_t stream)
{
    const float* x      = (const float*)d_in[0];   // [B,T,C]
    const float* w_qkv  = (const float*)d_in[1];   // [3C,C]
    const float* w_proj = (const float*)d_in[2];   // [C,C]
    float* out = (float*)d_out;                    // [B,T,C] fp32

    const size_t per = (size_t)Bn * Hn * Tn * Dn;  // 4,718,592

    ushort_t* xb  = (ushort_t*)d_ws;               // 8192*576
    ushort_t* wqb = xb  + (size_t)Mn * Cn;         // 1728*576
    ushort_t* wpb = wqb + (size_t)3 * Cn * Cn;     // 576*576
    ushort_t* qkv = wpb + (size_t)Cn * Cn;         // 3*per (q | k | v^T)
    ushort_t* yb  = qkv + 3 * per;                 // 8192*576
    ushort_t* zb  = yb  + (size_t)Mn * Cn;         // 256 B of zeros (Q/K pad source)

    hipMemsetAsync(zb, 0, 256, stream);

    // fused casts (fp32 -> bf16)
    const int na4 = Mn * Cn / 4, nb4 = 3 * Cn * Cn / 4, nc4 = Cn * Cn / 4;
    cast3<<<dim3((na4 + nb4 + nc4 + 255) / 256), dim3(256), 0, stream>>>(
        x, xb, na4, w_qkv, wqb, nb4, w_proj, wpb, nc4);

    // QKV GEMM (M=8192, N=1728): 1728 blocks, XCD-swizzled
    gemm_mfma<0><<<dim3((Mn / 128) * 27), dim3(256), 0, stream>>>(xb, wqb, qkv, nullptr);

    // causal attention (ALiBi bias is exactly zero on the unmasked region)
    attn_mfma<<<dim3((Tn / 128) * Bn * Hn), dim3(512), 0, stream>>>(
        qkv, qkv + per, qkv + 2 * per, yb, zb);

    // output projection (M=8192, N=576) -> fp32: 576 blocks, XCD-swizzled
    gemm_mfma<1><<<dim3((Mn / 128) * 9), dim3(256), 0, stream>>>(yb, wpb, nullptr, out);
}

// Round 10
// 186.546 us; speedup vs baseline: 1.7173x; 1.6086x over previous
//
#include <hip/hip_runtime.h>
#include <math.h>

// Problem constants (B=4, T=2048, C=576, H=12, D=48)
#define Bn 4
#define Tn 2048
#define Cn 576
#define Hn 12
#define Dn 48
#define Mn (Bn*Tn)          // 8192 rows

// log2(e) / sqrt(48) — folded into q so attention uses exp2 directly
#define QSCALE (1.4426950408889634f * 0.14433756729740643f)

typedef short  short8  __attribute__((ext_vector_type(8)));   // 8 bf16 (4 VGPRs)
typedef float  floatx4 __attribute__((ext_vector_type(4)));   // MFMA acc
typedef unsigned short ushort_t;
typedef unsigned short ushort8_t __attribute__((ext_vector_type(8))); // 16B

static __device__ __forceinline__ unsigned short f2bf(float f) {
    union { float f; unsigned int u; } v; v.f = f;
    unsigned int r = v.u + 0x7FFFu + ((v.u >> 16) & 1u);   // round-to-nearest-even
    return (unsigned short)(r >> 16);
}

// truncation-pack two fp32 -> packed bf16x2 (P >= 0, rel err <= 2^-8)
static __device__ __forceinline__ unsigned int pack_trunc(float a, float b) {
    union { float f; unsigned int u; } ua, ub; ua.f = a; ub.f = b;
    return (ua.u >> 16) | (ub.u & 0xFFFF0000u);
}

// async global->LDS, 16B per lane; lane l's data lands at lds + l*16 (lane-linear)
static __device__ __forceinline__ void gload16(void* lds, const void* g) {
    __builtin_amdgcn_global_load_lds(
        (const __attribute__((address_space(1))) void*)g,
        (__attribute__((address_space(3))) void*)lds, 16, 0, 0);
}

// ---------------------------------------------------------------------------
// fused fp32 -> bf16 cast of all three inputs (one launch)
// ---------------------------------------------------------------------------
__global__ __launch_bounds__(256)
void cast3(const float* __restrict__ a, ushort_t* __restrict__ oa, int na4,
           const float* __restrict__ b, ushort_t* __restrict__ ob, int nb4,
           const float* __restrict__ c, ushort_t* __restrict__ oc, int nc4)
{
    int i = blockIdx.x * 256 + threadIdx.x;
    const float* src; ushort_t* dst; int idx;
    if (i < na4)                  { src = a; dst = oa; idx = i; }
    else if (i < na4 + nb4)       { src = b; dst = ob; idx = i - na4; }
    else if (i < na4 + nb4 + nc4) { src = c; dst = oc; idx = i - na4 - nb4; }
    else return;
    float4 v = ((const float4*)src)[idx];
    ushort4 o;
    o.x = f2bf(v.x); o.y = f2bf(v.y); o.z = f2bf(v.z); o.w = f2bf(v.w);
    ((ushort4*)dst)[idx] = o;
}

// ---------------------------------------------------------------------------
// MFMA bf16 GEMM: out = A[M,576] @ W[N,576]^T.
// ROUND-5 K-loop (measured non-pathological: global_load_lds double-buffer,
// one barrier per K-step, NO large register arrays -> no scratch spill).
// Block tile MTILE(M) x 64(N), BK=32, 4 waves stacked in M.
// XCD SWIZZLE: bid = xcd + 8*slot; n = slot%NB; m-group = xcd + 8*(slot/NB).
// All NB n-blocks of one m-group land on one XCD -> A-tile fetched ~once, W
// resident in that XCD's L2.
// COALESCED EPILOGUE (MODE 0): C staged to LDS (reusing staging buffers), then
// cooperative 16B-chunk writes (q/k: 96B head-runs; v: LDS transpose -> 512B
// runs in [B,H,48,T]).  MODE 1: fp32 row-major direct (64B runs).
// ---------------------------------------------------------------------------
template<int MODE, int MTILE>
__global__ __launch_bounds__(256)
void gemm_mfma(const ushort_t* __restrict__ A, const ushort_t* __restrict__ W,
               ushort_t* __restrict__ outb, float* __restrict__ outf)
{
    constexpr int SA   = MTILE / 16;      // A segments
    constexpr int NSEG = SA + 4;          // + B segments (NTILE=64)
    constexpr int PW   = NSEG / 4;        // staging loads per wave per K-step
    constexpr int MF   = MTILE / 64;      // m-frags per wave
    constexpr int NB   = (MODE == 0) ? 27 : 9;
    __shared__ __align__(16) ushort_t Ls[2][NSEG][512];

    const int tid  = threadIdx.x;
    const int wave = tid >> 6;
    const int lane = tid & 63;
    const int m    = lane & 15;
    const int g    = lane >> 4;
    const int bid  = blockIdx.x;
    const int xcd  = bid & 7;
    const int slot = bid >> 3;
    const int n0   = (slot % NB) * 64;
    const int m0   = (xcd + 8 * (slot / NB)) * MTILE;

    floatx4 acc[MF][4];
    #pragma unroll
    for (int i = 0; i < MF; ++i)
        #pragma unroll
        for (int j = 0; j < 4; ++j)
            acc[i][j] = (floatx4){0.f, 0.f, 0.f, 0.f};

    const char* gp[PW];
    int         si[PW];
    #pragma unroll
    for (int i = 0; i < PW; ++i) {
        int s = wave + i * 4;
        si[i] = s;
        gp[i] = (s < SA)
            ? (const char*)(A + (size_t)(m0 + s * 16 + m) * Cn + g * 8)
            : (const char*)(W + (size_t)(n0 + (s - SA) * 16 + m) * Cn + g * 8);
    }

    // prologue: stage K-step 0 into buf 0
    #pragma unroll
    for (int i = 0; i < PW; ++i) { gload16(&Ls[0][si[i]][0], gp[i]); gp[i] += 64; }
    __syncthreads();

    int buf = 0;
    for (int k0 = 0; k0 < Cn; k0 += 32) {
        if (k0 + 32 < Cn) {     // issue next K-step into the other buffer (async)
            #pragma unroll
            for (int i = 0; i < PW; ++i) { gload16(&Ls[buf ^ 1][si[i]][0], gp[i]); gp[i] += 64; }
        }
        short8 bf4[4];
        #pragma unroll
        for (int j = 0; j < 4; ++j) bf4[j] = *(const short8*)&Ls[buf][SA + j][lane * 8];
        #pragma unroll
        for (int i = 0; i < MF; ++i) {
            short8 af = *(const short8*)&Ls[buf][wave * MF + i][lane * 8];
            #pragma unroll
            for (int j = 0; j < 4; ++j)
                acc[i][j] = __builtin_amdgcn_mfma_f32_16x16x32_bf16(af, bf4[j], acc[i][j], 0, 0, 0);
        }
        __syncthreads();        // drains vmcnt -> next buf ready; protects overwrite
        buf ^= 1;
    }

    // ---- epilogue: C/D layout col = lane&15 (n), row = (lane>>4)*4 + reg ----
    const size_t per = (size_t)Bn * Hn * Tn * Dn;
    if (MODE == 0) {
        const int which = n0 / Cn;
        const int nb    = n0 - which * Cn;
        const int b     = m0 >> 11;          // MTILE | 2048 -> no straddle
        const int t0g   = m0 & 2047;
        ushort_t* Lc = (ushort_t*)&Ls[0][0][0];   // reuse staging LDS (40KB)
        if (which == 2) {
            // stage transposed: Lv[col(64)][row(MTILE)+8 pad]
            constexpr int RS = MTILE + 8;
            #pragma unroll
            for (int i = 0; i < MF; ++i)
                #pragma unroll
                for (int j = 0; j < 4; ++j) {
                    ushort4 pk;
                    pk.x = f2bf(acc[i][j][0]); pk.y = f2bf(acc[i][j][1]);
                    pk.z = f2bf(acc[i][j][2]); pk.w = f2bf(acc[i][j][3]);
                    *(ushort4*)&Lc[(j * 16 + m) * RS + wave * (MTILE / 4) + i * 16 + g * 4] = pk;
                }
            __syncthreads();
            // write [B,H,48,T]: 16B chunks, consecutive threads -> consecutive t
            constexpr int CPC = MTILE / 8;            // chunks per col
            constexpr int NIT = 64 * CPC / 256;       // write iterations
            #pragma unroll
            for (int it = 0; it < NIT; ++it) {
                int c    = tid + it * 256;
                int col  = c / CPC;
                int rowc = (c - col * CPC) * 8;
                int n    = nb + col;
                int h    = n / 48;
                int d    = n - h * 48;
                ushort_t* dst = outb + 2 * per
                    + (((size_t)(b * Hn + h) * Dn + d) * Tn) + t0g + rowc;
                *(ushort8_t*)dst = *(const ushort8_t*)&Lc[col * RS + rowc];
            }
        } else {
            const float sc = (which == 0) ? QSCALE : 1.0f;
            // stage row-major: Lr[row(MTILE)][col(64)+16 pad] (exactly 40KB at 256)
            #pragma unroll
            for (int i = 0; i < MF; ++i)
                #pragma unroll
                for (int j = 0; j < 4; ++j)
                    #pragma unroll
                    for (int r = 0; r < 4; ++r)
                        Lc[(wave * (MTILE / 4) + i * 16 + g * 4 + r) * 80 + j * 16 + m] =
                            f2bf(acc[i][j][r] * sc);
            __syncthreads();
            // write [B,H,T,48]: 16B chunks never straddle a head (8 | 48)
            constexpr int NIT = MTILE * 8 / 256;
            #pragma unroll
            for (int it = 0; it < NIT; ++it) {
                int c   = tid + it * 256;
                int row = c >> 3;
                int c8  = (c & 7) * 8;
                int n   = nb + c8;
                int h   = n / 48;
                int d   = n - h * 48;
                ushort_t* dst = outb + (size_t)which * per
                    + (((size_t)(b * Hn + h) * Tn + t0g + row) * Dn) + d;
                *(ushort8_t*)dst = *(const ushort8_t*)&Lc[row * 80 + c8];
            }
        }
    } else {
        #pragma unroll
        for (int i = 0; i < MF; ++i) {
            #pragma unroll
            for (int r = 0; r < 4; ++r) {
                int mrow = m0 + wave * (MTILE / 4) + i * 16 + g * 4 + r;
                #pragma unroll
                for (int j = 0; j < 4; ++j)
                    outf[(size_t)mrow * Cn + n0 + j * 16 + m] = acc[i][j][r];
            }
        }
    }
}

// ---------------------------------------------------------------------------
// Flash attention via S^T, no-max softmax, bf16 MFMA (round-7 kernel, 64.3us,
// + round-9 interleaved-qt grid for CU load balance).
// Q-tile 128, 512 threads (8 waves x 16 q). K-tile 64, double-buffered
// global_load_lds staging, lane-linear segments. Ps aliases dead Q strip.
// ---------------------------------------------------------------------------
__global__ __launch_bounds__(512, 6)
void attn_mfma(const ushort_t* __restrict__ Q, const ushort_t* __restrict__ K,
               const ushort_t* __restrict__ V, ushort_t* __restrict__ Y,
               const ushort_t* __restrict__ zb)
{
    __shared__ __align__(16) ushort_t QPs[16][512];    // Q tile, then reused as P^T
    __shared__ __align__(16) ushort_t Ks[2][8][512];   // [buf][(ktile t, kc)]
    __shared__ __align__(16) ushort_t Vs[2][6][512];   // [buf][(dtile t, kc)]

    const int id   = blockIdx.x;
    const int kk   = id / 48;
    const int bh   = id - kk * 48;
    const int QT   = (kk & 1) ? (kk >> 1) : (15 - (kk >> 1));   // interleave big/small
    const int tid  = threadIdx.x;
    const int wave = tid >> 6;       // 0..7
    const int lane = tid & 63;
    const int m    = lane & 15;
    const int g    = lane >> 4;
    const int q0   = QT * 128;
    const int nkt  = 2 * QT + 2;     // 64-row K tiles to process

    const ushort_t* Qp = Q + (size_t)bh * Tn * Dn;
    const ushort_t* Kp = K + (size_t)bh * Tn * Dn;
    const ushort_t* Vp = V + (size_t)bh * Dn * Tn;     // [48][T]

    // ---- Q staging: wave w stages segs 2w,2w+1 (rows q0+w*16+m); pad -> zeros ----
    {
        const char* qrp = (const char*)(Qp + (size_t)(q0 + wave * 16 + m) * Dn);
        gload16(&QPs[wave * 2 + 0][0], qrp + g * 16);
        gload16(&QPs[wave * 2 + 1][0], (g < 2) ? (qrp + 64 + g * 16) : (const char*)zb);
    }

    // ---- per-lane K/V staging pointers (wave w owns K seg w; V seg w for w<6) ----
    const bool  kpad = ((wave & 1) == 1) && (g >= 2);
    const char* kptr = kpad ? (const char*)zb
        : (const char*)(Kp + (size_t)((wave >> 1) * 16 + m) * Dn) + (wave & 1) * 64 + g * 16;
    const int   kadv = kpad ? 0 : 64 * Dn * 2;         // 64 K-rows per tile
    const char* vptr = (const char*)(Vp + (size_t)((wave >> 1) * 16 + m) * Tn)
                       + (wave & 1) * 64 + g * 16;     // valid only for wave<6
    const int   vadv = 64 * 2;                         // 64 V^T-cols per tile

    // prologue: stage K/V tile 0 into buf 0
    gload16(&Ks[0][wave][0], kptr); kptr += kadv;
    if (wave < 6) { gload16(&Vs[0][wave][0], vptr); vptr += vadv; }
    __syncthreads();   // drains vmcnt -> Q + tile0 ready

    // loop-invariant B-fragments (Q); QPs strip (wave-private) then dead -> P^T
    short8 bq[2];
    bq[0] = *(const short8*)&QPs[wave * 2 + 0][lane * 8];
    bq[1] = *(const short8*)&QPs[wave * 2 + 1][lane * 8];

    floatx4 acc[3];
    #pragma unroll
    for (int t = 0; t < 3; ++t) acc[t] = (floatx4){0.f, 0.f, 0.f, 0.f};
    float l_tot = 0.f;
    const int qrow  = q0 + wave * 16 + m;    // this lane's global query row
    const int qwmin = q0 + wave * 16;        // wave's min query row
    const int qwmax = qwmin + 15;            // wave's max query row

    for (int jt = 0; jt < nkt; ++jt) {
        const int cur = jt & 1;
        const int j0  = jt * 64;
        // issue async staging for tile jt+1 (overlaps this tile's compute)
        if (jt + 1 < nkt) {
            gload16(&Ks[cur ^ 1][wave][0], kptr); kptr += kadv;
            if (wave < 6) { gload16(&Vs[cur ^ 1][wave][0], vptr); vptr += vadv; }
        }

        if (j0 <= qwmax) {   // wave-uniform: at least one unmasked element
            // ---- S^T = K Q^T : D[m=j (4 tiles)][n=q] ----
            floatx4 s[4];
            #pragma unroll
            for (int t = 0; t < 4; ++t) {
                s[t] = (floatx4){0.f, 0.f, 0.f, 0.f};
                #pragma unroll
                for (int kc = 0; kc < 2; ++kc) {
                    short8 ak = *(const short8*)&Ks[cur][t * 2 + kc][lane * 8];
                    s[t] = __builtin_amdgcn_mfma_f32_16x16x32_bf16(ak, bq[kc], s[t], 0, 0, 0);
                }
            }

            // ---- mask (only if tile straddles diagonal) + exp2 + partial sum ----
            float p[4][4];
            float lsum = 0.f;
            if (j0 + 63 > qwmin) {
                #pragma unroll
                for (int t = 0; t < 4; ++t)
                    #pragma unroll
                    for (int r = 0; r < 4; ++r) {
                        int j = j0 + t * 16 + g * 4 + r;
                        float v = (j <= qrow) ? s[t][r] : -1e30f;
                        float e = __builtin_amdgcn_exp2f(v);
                        p[t][r] = e; lsum += e;
                    }
            } else {
                #pragma unroll
                for (int t = 0; t < 4; ++t)
                    #pragma unroll
                    for (int r = 0; r < 4; ++r) {
                        float e = __builtin_amdgcn_exp2f(s[t][r]);
                        p[t][r] = e; lsum += e;
                    }
            }
            lsum += __shfl_xor(lsum, 16);
            lsum += __shfl_xor(lsum, 32);
            l_tot += lsum;

            // ---- store P^T in B-frag order into the (dead) Q strip ----
            #pragma unroll
            for (int t = 0; t < 4; ++t) {
                uint2 w2;
                w2.x = pack_trunc(p[t][0], p[t][1]);
                w2.y = pack_trunc(p[t][2], p[t][3]);
                *(uint2*)&QPs[wave * 2 + (t >> 1)]
                             [(2 * (t & 1) + (g >> 1)) * 128 + m * 8 + (g & 1) * 4] = w2;
            }
            // wave-private strip: drain this wave's LDS writes, no barrier needed
            asm volatile("s_waitcnt lgkmcnt(0)" ::: "memory");

            // ---- O^T += V^T P^T : D[m=d (3 tiles)][n=q] ----
            #pragma unroll
            for (int kc = 0; kc < 2; ++kc) {
                short8 bp = *(const short8*)&QPs[wave * 2 + kc][lane * 8];
                #pragma unroll
                for (int t = 0; t < 3; ++t) {
                    short8 av = *(const short8*)&Vs[cur][t * 2 + kc][lane * 8];
                    acc[t] = __builtin_amdgcn_mfma_f32_16x16x32_bf16(av, bp, acc[t], 0, 0, 0);
                }
            }
        }

        __syncthreads();   // next tile staged (vmcnt drain) + cur-buf reads done
    }

    // ---- epilogue: lane holds O^T[d = t*16+g*4+r][qrow]; normalize, store ----
    const float inv = 1.0f / l_tot;
    const int b = bh / Hn;
    const int h = bh - b * Hn;
    ushort_t* yp = Y + ((size_t)(b * Tn + qrow)) * Cn + h * Dn;
    #pragma unroll
    for (int t = 0; t < 3; ++t) {
        ushort4 o;
        o.x = f2bf(acc[t][0] * inv);
        o.y = f2bf(acc[t][1] * inv);
        o.z = f2bf(acc[t][2] * inv);
        o.w = f2bf(acc[t][3] * inv);
        *(ushort4*)&yp[t * 16 + g * 4] = o;
    }
}

// ---------------------------------------------------------------------------
extern "C" void kernel_launch(void* const* d_in, const int* in_sizes, int n_in,
                              void* d_out, int out_size, void* d_ws, size_t ws_size,
                              hipStream_t stream)
{
    const float* x      = (const float*)d_in[0];   // [B,T,C]
    const float* w_qkv  = (const float*)d_in[1];   // [3C,C]
    const float* w_proj = (const float*)d_in[2];   // [C,C]
    float* out = (float*)d_out;                    // [B,T,C] fp32

    const size_t per = (size_t)Bn * Hn * Tn * Dn;  // 4,718,592

    ushort_t* xb  = (ushort_t*)d_ws;               // 8192*576
    ushort_t* wqb = xb  + (size_t)Mn * Cn;         // 1728*576
    ushort_t* wpb = wqb + (size_t)3 * Cn * Cn;     // 576*576
    ushort_t* qkv = wpb + (size_t)Cn * Cn;         // 3*per (q | k | v^T)
    ushort_t* yb  = qkv + 3 * per;                 // 8192*576
    ushort_t* zb  = yb  + (size_t)Mn * Cn;         // 256 B of zeros (Q/K pad source)

    hipMemsetAsync(zb, 0, 256, stream);

    // fused casts (fp32 -> bf16)
    const int na4 = Mn * Cn / 4, nb4 = 3 * Cn * Cn / 4, nc4 = Cn * Cn / 4;
    cast3<<<dim3((na4 + nb4 + nc4 + 255) / 256), dim3(256), 0, stream>>>(
        x, xb, na4, w_qkv, wqb, nb4, w_proj, wpb, nc4);

    // QKV GEMM (M=8192, N=1728): 864 blocks = 8 XCD x (32/8 m-groups x 27 n)
    gemm_mfma<0, 256><<<dim3((Mn / 256) * 27), dim3(256), 0, stream>>>(xb, wqb, qkv, nullptr);

    // causal attention (ALiBi bias is exactly zero on the unmasked region)
    attn_mfma<<<dim3((Tn / 128) * Bn * Hn), dim3(512), 0, stream>>>(
        qkv, qkv + per, qkv + 2 * per, yb, zb);

    // output projection (M=8192, N=576) -> fp32: 576 blocks, XCD-swizzled
    gemm_mfma<1, 128><<<dim3((Mn / 128) * 9), dim3(256), 0, stream>>>(yb, wpb, nullptr, out);
}